// Round 1
// baseline (229.268 us; speedup 1.0000x reference)
//
#include <hip/hip_runtime.h>

// Problem constants: B=2, N=1024, U=V=512, F_IN=1, F=64, L=4
static const int NB = 1024;

// ---- norm: column sums of mask = ((1-adj)!=0), partial per block via atomicAdd
__global__ void k_count(const float* __restrict__ adj, float* __restrict__ normf) {
    int b = blockIdx.x >> 2, cc = blockIdx.x & 3, rc = blockIdx.y;
    int col = cc * 256 + threadIdx.x;
    const float* p = adj + (size_t)b * NB * NB + (size_t)rc * 32 * NB + col;
    float cnt = 0.f;
#pragma unroll 8
    for (int r = 0; r < 32; ++r) {
        float a = p[(size_t)r * NB];
        cnt += ((1.0f - a) != 0.0f) ? 1.0f : 0.0f;
    }
    atomicAdd(&normf[b * NB + col], cnt);
}

// ---- clamp to >=1 and global max (float-as-int atomicMax, values > 0)
__global__ void k_clampmax(float* __restrict__ normf, int* __restrict__ nmax) {
    int i = blockIdx.x * 256 + threadIdx.x;
    float v = fmaxf(normf[i], 1.0f);
    normf[i] = v;
    atomicMax(nmax, __float_as_int(v));
}

// ---- wvuT[b][i][j] = wvu[b][j][i]
__global__ void k_transpose(const float* __restrict__ w, float* __restrict__ wT) {
    __shared__ float tile[32][33];
    int b = blockIdx.z;
    int xb = blockIdx.x * 32, yb = blockIdx.y * 32;
    const float* src = w + (size_t)b * 512 * 512;
    float* dst = wT + (size_t)b * 512 * 512;
    int tx = threadIdx.x, ty = threadIdx.y; // 32 x 8
#pragma unroll
    for (int k = 0; k < 32; k += 8)
        tile[ty + k][tx] = src[(size_t)(yb + ty + k) * 512 + xb + tx];
    __syncthreads();
#pragma unroll
    for (int k = 0; k < 32; k += 8)
        dst[(size_t)(xb + ty + k) * 512 + yb + tx] = tile[tx][ty + k];
}

// ---- x0 = relu(nf @ W_init + b_init)   (F_IN = 1)
__global__ void k_x0(const float* __restrict__ nf, const float* __restrict__ Wi,
                     const float* __restrict__ bi, float* __restrict__ x0) {
    int idx = blockIdx.x * 256 + threadIdx.x; // < 131072
    int f = idx & 63, bn = idx >> 6;
    float v = fmaf(nf[bn], Wi[f], bi[f]);
    x0[idx] = fmaxf(v, 0.f);
}

// ---- edge pass: summed + norm-ratio + W_edge_feat matmul fused.
// One wave per row (b,i); lane k in [0,63) owns output feature k of "summed",
// lane 63 carries the norm ratio. Then edge_emb = relu(ein @ Wef) in-block.
__global__ void __launch_bounds__(256) k_edge(
    const float* __restrict__ adj, const float* __restrict__ wvu,
    const float* __restrict__ wvuT, const float* __restrict__ nf,
    const float* __restrict__ normf, const int* __restrict__ nmaxp,
    const float* __restrict__ Wee, const float* __restrict__ Wef,
    float* __restrict__ edge) {
    __shared__ float s_adj[4][1024];
    __shared__ float s_w[4][1024];
    __shared__ float s_nf[1024];
    __shared__ float s_wef[64][64];
    __shared__ float s_ein[4][64];
    int tid = threadIdx.x;
    int g0 = blockIdx.x * 4;
    int b = g0 >> 10, i0 = g0 & 1023;
    const bool top = (i0 < 512);
#pragma unroll
    for (int t = tid; t < 1024; t += 256) s_nf[t] = nf[b * 1024 + t];
    for (int t = tid; t < 4096; t += 256) {
        int r = t >> 10, j = t & 1023;
        s_adj[r][j] = adj[(size_t)b * 1048576 + (size_t)(i0 + r) * 1024 + j];
    }
    if (top) {
        for (int t = tid; t < 4096; t += 256) {
            int r = t >> 10, j = t & 1023;
            s_w[r][j] = (j < 512) ? 0.0f
                : wvuT[(size_t)b * 262144 + (size_t)(i0 + r) * 512 + (j - 512)];
        }
    } else {
        for (int t = tid; t < 4096; t += 256) {
            int r = t >> 10, j = t & 1023;
            s_w[r][j] = (j < 512)
                ? wvu[(size_t)b * 262144 + (size_t)(i0 - 512 + r) * 512 + j] : 0.0f;
        }
    }
    for (int t = tid; t < 4096; t += 256) s_wef[t >> 6][t & 63] = Wef[t];
    __syncthreads();

    int row = tid >> 6, lane = tid & 63;
    float W0 = 0.f, W1 = 0.f;
    if (lane < 63) { W0 = Wee[lane]; W1 = Wee[63 + lane]; }
    float acc = 0.f;
#pragma unroll 2
    for (int j = 0; j < 1024; j += 4) {
        float4 a4 = *(const float4*)&s_adj[row][j];
        float4 w4 = *(const float4*)&s_w[row][j];
        float4 n4 = *(const float4*)&s_nf[j];
        float m, c;
        m = ((1.0f - a4.x) != 0.0f) ? 1.0f : 0.0f;
        c = fmaxf(fmaf(w4.x, W0, n4.x * W1), 0.0f);
        acc = fmaf(m, c, acc);
        m = ((1.0f - a4.y) != 0.0f) ? 1.0f : 0.0f;
        c = fmaxf(fmaf(w4.y, W0, n4.y * W1), 0.0f);
        acc = fmaf(m, c, acc);
        m = ((1.0f - a4.z) != 0.0f) ? 1.0f : 0.0f;
        c = fmaxf(fmaf(w4.z, W0, n4.z * W1), 0.0f);
        acc = fmaf(m, c, acc);
        m = ((1.0f - a4.w) != 0.0f) ? 1.0f : 0.0f;
        c = fmaxf(fmaf(w4.w, W0, n4.w * W1), 0.0f);
        acc = fmaf(m, c, acc);
    }
    int i = i0 + row;
    float nv = normf[b * 1024 + i];
    float nmax = __int_as_float(*nmaxp);
    float ein = (lane < 63) ? (acc / nv) : (nv / nmax);
    s_ein[row][lane] = ein;
    __syncthreads();
    float acc2 = 0.f;
#pragma unroll 8
    for (int c = 0; c < 64; ++c)
        acc2 = fmaf(s_ein[row][c], s_wef[c][lane], acc2);
    edge[(size_t)(g0 + row) * 64 + lane] = fmaxf(acc2, 0.f);
}

// ---- one message-passing layer, fused agg + msg + upd.
// Block handles 4 rows of one (batch, half). agg uses wvu/wvuT rows (contiguous).
template <int LAST>
__global__ void __launch_bounds__(256) k_layer(
    const float* __restrict__ x_in, float* __restrict__ x_out,
    const float* __restrict__ wvu, const float* __restrict__ wvuT,
    const float* __restrict__ normf, const float* __restrict__ edge,
    const float* __restrict__ Wm, const float* __restrict__ Wu) {
    __shared__ float s_wT[512][4];
    __shared__ float s_x[4][64];
    __shared__ float s_e[4][64];
    __shared__ float s_part[4][4][64];
    __shared__ float s_agg[4][64];
    __shared__ float s_msg[4][64];
    int tid = threadIdx.x;
    int g0 = blockIdx.x * 4;
    int b = g0 >> 10, i0 = g0 & 1023;
    bool top = (i0 < 512);
    const float* wsrc = top ? (wvuT + (size_t)b * 262144 + (size_t)i0 * 512)
                            : (wvu + (size_t)b * 262144 + (size_t)(i0 - 512) * 512);
    for (int t = tid; t < 2048; t += 256) {
        int r = t >> 9, j = t & 511;
        s_wT[j][r] = wsrc[(size_t)r * 512 + j];
    }
    {
        int r = tid >> 6, c = tid & 63;
        s_x[r][c] = x_in[(size_t)(g0 + r) * 64 + c];
        s_e[r][c] = edge[(size_t)(g0 + r) * 64 + c];
    }
    __syncthreads();
    int f = tid & 63, q = tid >> 6;
    const float* xb = x_in + ((size_t)b * 1024 + (top ? 512 : 0)) * 64 + f;
    float a0 = 0, a1 = 0, a2 = 0, a3 = 0;
#pragma unroll 4
    for (int jj = 0; jj < 128; ++jj) {
        int j = q * 128 + jj;
        float xv = xb[(size_t)j * 64];
        float4 w4 = *(const float4*)&s_wT[j][0];
        a0 = fmaf(w4.x, xv, a0);
        a1 = fmaf(w4.y, xv, a1);
        a2 = fmaf(w4.z, xv, a2);
        a3 = fmaf(w4.w, xv, a3);
    }
    s_part[q][0][f] = a0; s_part[q][1][f] = a1;
    s_part[q][2][f] = a2; s_part[q][3][f] = a3;
    __syncthreads();
    float aggv = s_part[0][q][f] + s_part[1][q][f] + s_part[2][q][f] + s_part[3][q][f];
    aggv /= normf[b * 1024 + i0 + q];
    s_agg[q][f] = aggv;
    __syncthreads();
    float mv = 0.f;
#pragma unroll 4
    for (int c = 0; c < 64; ++c) mv = fmaf(s_agg[q][c], Wm[c * 64 + f], mv);
#pragma unroll 4
    for (int c = 0; c < 64; ++c) mv = fmaf(s_e[q][c], Wm[(64 + c) * 64 + f], mv);
    mv = fmaxf(mv, 0.f);
    s_msg[q][f] = mv;
    __syncthreads();
    float h = 0.f;
#pragma unroll 4
    for (int c = 0; c < 64; ++c) h = fmaf(s_x[q][c], Wu[c * 64 + f], h);
#pragma unroll 4
    for (int c = 0; c < 64; ++c) h = fmaf(s_msg[q][c], Wu[(64 + c) * 64 + f], h);
    if (!LAST) h = fmaxf(h, 0.f);
    x_out[(size_t)(g0 + q) * 64 + f] = h;
}

extern "C" void kernel_launch(void* const* d_in, const int* in_sizes, int n_in,
                              void* d_out, int out_size, void* d_ws, size_t ws_size,
                              hipStream_t stream) {
    const float* nf  = (const float*)d_in[0];
    const float* adj = (const float*)d_in[1];
    const float* wvu = (const float*)d_in[2];
    const float* Wi  = (const float*)d_in[3];
    const float* bi  = (const float*)d_in[4];
    const float* Wee = (const float*)d_in[5];
    const float* Wef = (const float*)d_in[6];
    const float* Wm  = (const float*)d_in[7];
    const float* Wu  = (const float*)d_in[8];
    float* out = (float*)d_out;
    float* ws = (float*)d_ws;

    float* wvuT  = ws;              // 524288 floats (2 MB)
    float* x0    = ws + 524288;     // 131072
    float* x1    = ws + 655360;     // 131072
    float* edge  = ws + 786432;     // 131072
    float* normf = ws + 917504;     // 2048
    int*   nmax  = (int*)(ws + 919552); // 1

    hipMemsetAsync(normf, 0, 2049 * sizeof(float), stream);
    k_count<<<dim3(8, 32), 256, 0, stream>>>(adj, normf);
    k_transpose<<<dim3(16, 16, 2), dim3(32, 8), 0, stream>>>(wvu, wvuT);
    k_clampmax<<<8, 256, 0, stream>>>(normf, nmax);
    k_x0<<<512, 256, 0, stream>>>(nf, Wi, bi, x0);
    k_edge<<<512, 256, 0, stream>>>(adj, wvu, wvuT, nf, normf, nmax, Wee, Wef, edge);
    k_layer<0><<<512, 256, 0, stream>>>(x0, x1, wvu, wvuT, normf, edge, Wm, Wu);
    k_layer<0><<<512, 256, 0, stream>>>(x1, x0, wvu, wvuT, normf, edge, Wm + 8192, Wu + 8192);
    k_layer<0><<<512, 256, 0, stream>>>(x0, x1, wvu, wvuT, normf, edge, Wm + 16384, Wu + 16384);
    k_layer<1><<<512, 256, 0, stream>>>(x1, out, wvu, wvuT, normf, edge, Wm + 24576, Wu + 24576);
}

// Round 3
// 204.922 us; speedup vs baseline: 1.1188x; 1.1188x over previous
//
#include <hip/hip_runtime.h>

// Problem constants: B=2, N=1024, U=V=512, F_IN=1, F=64, L=4
#define NTOT 1024
#define HALF 512

// ---------- prep: norm partials (atomic-free) + wvu transpose + x0 ----------
// grid 512 x 256. Each block does one share of each of the three jobs.
__global__ void __launch_bounds__(256) k_prep(
    const float* __restrict__ adj, const float* __restrict__ wvu,
    const float* __restrict__ nf, const float* __restrict__ Wi,
    const float* __restrict__ bi,
    float* __restrict__ wvuT, float* __restrict__ x0,
    float* __restrict__ partials, int* __restrict__ nmax) {
    int bid = blockIdx.x, tid = threadIdx.x;
    if (bid == 0 && tid == 0) *nmax = 0;
    // norm partials: block -> (batch cb, colchunk cc of 256, rowchunk rc of 16)
    {
        int cb = bid >> 8, cc = (bid >> 6) & 3, rc = bid & 63;
        int col = cc * 256 + tid;
        const float* p = adj + (size_t)cb * NTOT * NTOT + (size_t)rc * 16 * NTOT + col;
        float s = 0.f;
#pragma unroll
        for (int r = 0; r < 16; ++r) s += 1.0f - p[(size_t)r * NTOT];
        partials[rc * 2048 + cb * NTOT + col] = s;
    }
    // transpose one 32x32 tile: block -> (tb, tile y, tile x)
    {
        __shared__ float tile[32][33];
        int tb = bid >> 8, tyi = (bid >> 4) & 15, txi = bid & 15;
        int xb = txi * 32, yb = tyi * 32;
        const float* src = wvu + (size_t)tb * HALF * HALF;
        float* dst = wvuT + (size_t)tb * HALF * HALF;
        int tx = tid & 31, ty = tid >> 5; // 32 x 8
#pragma unroll
        for (int k = 0; k < 32; k += 8)
            tile[ty + k][tx] = src[(size_t)(yb + ty + k) * HALF + xb + tx];
        __syncthreads();
#pragma unroll
        for (int k = 0; k < 32; k += 8)
            dst[(size_t)(xb + ty + k) * HALF + yb + tx] = tile[tx][ty + k];
    }
    // x0 chunk
    {
        int e = bid * 256 + tid;
        int f = e & 63, bn = e >> 6;
        x0[e] = fmaxf(fmaf(nf[bn], Wi[f], bi[f]), 0.f);
    }
}

// ---------- finish norm: sum 64 partials/col, clamp, global max ----------
__global__ void k_normfin(const float* __restrict__ partials,
                          float* __restrict__ normf, int* __restrict__ nmax) {
    __shared__ float red[256];
    int t = threadIdx.x;
    int gc = blockIdx.x * 256 + t;
    float s = 0.f;
#pragma unroll 8
    for (int rc = 0; rc < 64; ++rc) s += partials[rc * 2048 + gc];
    float v = fmaxf(s, 1.0f);
    normf[gc] = v;
    red[t] = v;
    __syncthreads();
    for (int o = 128; o > 0; o >>= 1) {
        if (t < o) red[t] = fmaxf(red[t], red[t + o]);
        __syncthreads();
    }
    if (t == 0) atomicMax(nmax, __float_as_int(red[0]));
}

// ---------- edge pass ----------
// 4 rows per block, one wave per row, lane = feature.
// Same-half j (w==0) collapsed to: |W1k| * (W1k>0 ? Sp : Sm),
//   Sp = sum_j m_ij relu(nf_j), Sm = sum_j m_ij relu(-nf_j)  (lane-parallel).
// Cross-half j: full relu(w*W0k + nf_j*W1k) loop over 512 j (broadcast LDS).
__global__ void __launch_bounds__(256) k_edge(
    const float* __restrict__ adj, const float* __restrict__ wvu,
    const float* __restrict__ wvuT, const float* __restrict__ nf,
    const float* __restrict__ normf, const int* __restrict__ nmaxp,
    const float* __restrict__ Wee, const float* __restrict__ Wef,
    float* __restrict__ edge) {
    __shared__ float s_adj[4][1024];
    __shared__ float s_w[4][512];
    __shared__ float s_nf[1024];
    __shared__ float s_wef[64][64];
    __shared__ float s_ein[4][64];
    int tid = threadIdx.x;
    int g0 = blockIdx.x * 4;
    int b = g0 >> 10, i0 = g0 & 1023;
    bool top = (i0 < 512);
    {
        const float4* src = (const float4*)(adj + (size_t)b * 1048576 + (size_t)i0 * 1024);
        float4* dst = (float4*)s_adj;
#pragma unroll
        for (int t = tid; t < 1024; t += 256) dst[t] = src[t];
        const float4* nsrc = (const float4*)(nf + b * 1024);
        ((float4*)s_nf)[tid] = nsrc[tid];
        const float* wsrc = top ? (wvuT + (size_t)b * 262144 + (size_t)i0 * 512)
                                : (wvu + (size_t)b * 262144 + (size_t)(i0 - 512) * 512);
        const float4* w4 = (const float4*)wsrc;
        float4* wds = (float4*)s_w;
#pragma unroll
        for (int t = tid; t < 512; t += 256) wds[t] = w4[t];
        const float4* wefs = (const float4*)Wef;
        float4* wefd = (float4*)s_wef;
#pragma unroll
        for (int t = tid; t < 1024; t += 256) wefd[t] = wefs[t];
    }
    __syncthreads();
    int lane = tid & 63, row = tid >> 6;
    int sameoff = top ? 0 : 512;
    int crossoff = top ? 512 : 0;
    // Sp/Sm: lanes = j over the same-half 512 columns
    float sp = 0.f, sm = 0.f;
#pragma unroll
    for (int it = 0; it < 8; ++it) {
        int j = sameoff + it * 64 + lane;
        float m = 1.0f - s_adj[row][j];
        float x = s_nf[j];
        sp = fmaf(m, fmaxf(x, 0.f), sp);
        sm = fmaf(m, fmaxf(-x, 0.f), sm);
    }
#pragma unroll
    for (int o = 32; o > 0; o >>= 1) {
        sp += __shfl_xor(sp, o, 64);
        sm += __shfl_xor(sm, o, 64);
    }
    float W0 = 0.f, W1 = 0.f;
    if (lane < 63) { W0 = Wee[lane]; W1 = Wee[63 + lane]; }
    float acc = fabsf(W1) * (W1 > 0.f ? sp : sm);
    const float* arow = &s_adj[row][crossoff];
    const float* nrow = &s_nf[crossoff];
    const float* wrow = &s_w[row][0];
#pragma unroll 4
    for (int q = 0; q < 128; ++q) {
        float4 a4 = *(const float4*)(arow + q * 4);
        float4 w4 = *(const float4*)(wrow + q * 4);
        float4 n4 = *(const float4*)(nrow + q * 4);
        float c;
        c = fmaxf(fmaf(w4.x, W0, n4.x * W1), 0.f); acc = fmaf(1.0f - a4.x, c, acc);
        c = fmaxf(fmaf(w4.y, W0, n4.y * W1), 0.f); acc = fmaf(1.0f - a4.y, c, acc);
        c = fmaxf(fmaf(w4.z, W0, n4.z * W1), 0.f); acc = fmaf(1.0f - a4.z, c, acc);
        c = fmaxf(fmaf(w4.w, W0, n4.w * W1), 0.f); acc = fmaf(1.0f - a4.w, c, acc);
    }
    int i = i0 + row;
    float nv = normf[b * 1024 + i];
    float nmaxv = __int_as_float(*nmaxp);
    float ein = (lane < 63) ? (acc / nv) : (nv / nmaxv);
    s_ein[row][lane] = ein;
    __syncthreads();
    float acc2 = 0.f;
#pragma unroll
    for (int c = 0; c < 64; ++c)
        acc2 = fmaf(s_ein[row][c], s_wef[c][lane], acc2);
    edge[(size_t)(g0 + row) * 64 + lane] = fmaxf(acc2, 0.f);
}

// ---------- one message-passing layer: agg + msg + upd fused ----------
template <int LAST>
__global__ void __launch_bounds__(256) k_layer(
    const float* __restrict__ x_in, float* __restrict__ x_out,
    const float* __restrict__ wvu, const float* __restrict__ wvuT,
    const float* __restrict__ normf, const float* __restrict__ edge,
    const float* __restrict__ Wm, const float* __restrict__ Wu) {
    __shared__ float s_wT[512][4];
    __shared__ float s_x[4][64];
    __shared__ float s_e[4][64];
    __shared__ float s_part[4][4][64];
    __shared__ float s_agg[4][64];
    __shared__ float s_msg[4][64];
    int tid = threadIdx.x;
    int g0 = blockIdx.x * 4;
    int b = g0 >> 10, i0 = g0 & 1023;
    bool top = (i0 < 512);
    const float* wsrc = top ? (wvuT + (size_t)b * 262144 + (size_t)i0 * 512)
                            : (wvu + (size_t)b * 262144 + (size_t)(i0 - 512) * 512);
    for (int t = tid; t < 2048; t += 256) {
        int r = t >> 9, j = t & 511;
        s_wT[j][r] = wsrc[(size_t)r * 512 + j];
    }
    {
        int r = tid >> 6, c = tid & 63;
        s_x[r][c] = x_in[(size_t)(g0 + r) * 64 + c];
        s_e[r][c] = edge[(size_t)(g0 + r) * 64 + c];
    }
    __syncthreads();
    int f = tid & 63, q = tid >> 6;
    const float* xb = x_in + ((size_t)b * 1024 + (top ? 512 : 0)) * 64 + f;
    float a0 = 0, a1 = 0, a2 = 0, a3 = 0;
#pragma unroll 4
    for (int jj = 0; jj < 128; ++jj) {
        int j = q * 128 + jj;
        float xv = xb[(size_t)j * 64];
        float4 w4 = *(const float4*)&s_wT[j][0];
        a0 = fmaf(w4.x, xv, a0);
        a1 = fmaf(w4.y, xv, a1);
        a2 = fmaf(w4.z, xv, a2);
        a3 = fmaf(w4.w, xv, a3);
    }
    s_part[q][0][f] = a0; s_part[q][1][f] = a1;
    s_part[q][2][f] = a2; s_part[q][3][f] = a3;
    __syncthreads();
    float aggv = s_part[0][q][f] + s_part[1][q][f] + s_part[2][q][f] + s_part[3][q][f];
    aggv /= normf[b * 1024 + i0 + q];
    s_agg[q][f] = aggv;
    __syncthreads();
    float mv = 0.f;
#pragma unroll 4
    for (int c = 0; c < 64; ++c) mv = fmaf(s_agg[q][c], Wm[c * 64 + f], mv);
#pragma unroll 4
    for (int c = 0; c < 64; ++c) mv = fmaf(s_e[q][c], Wm[(64 + c) * 64 + f], mv);
    mv = fmaxf(mv, 0.f);
    s_msg[q][f] = mv;
    __syncthreads();
    float h = 0.f;
#pragma unroll 4
    for (int c = 0; c < 64; ++c) h = fmaf(s_x[q][c], Wu[c * 64 + f], h);
#pragma unroll 4
    for (int c = 0; c < 64; ++c) h = fmaf(s_msg[q][c], Wu[(64 + c) * 64 + f], h);
    if (!LAST) h = fmaxf(h, 0.f);
    x_out[(size_t)(g0 + q) * 64 + f] = h;
}

extern "C" void kernel_launch(void* const* d_in, const int* in_sizes, int n_in,
                              void* d_out, int out_size, void* d_ws, size_t ws_size,
                              hipStream_t stream) {
    const float* nf  = (const float*)d_in[0];
    const float* adj = (const float*)d_in[1];
    const float* wvu = (const float*)d_in[2];
    const float* Wi  = (const float*)d_in[3];
    const float* bi  = (const float*)d_in[4];
    const float* Wee = (const float*)d_in[5];
    const float* Wef = (const float*)d_in[6];
    const float* Wm  = (const float*)d_in[7];
    const float* Wu  = (const float*)d_in[8];
    float* out = (float*)d_out;
    float* ws = (float*)d_ws;

    float* wvuT     = ws;               // 524288 floats
    float* x0       = ws + 524288;      // 131072
    float* x1       = ws + 655360;      // 131072
    float* edge     = ws + 786432;      // 131072
    float* normf    = ws + 917504;      // 2048
    float* partials = ws + 919552;      // 131072
    int*   nmax     = (int*)(ws + 1050624);

    k_prep<<<512, 256, 0, stream>>>(adj, wvu, nf, Wi, bi, wvuT, x0, partials, nmax);
    k_normfin<<<8, 256, 0, stream>>>(partials, normf, nmax);
    k_edge<<<512, 256, 0, stream>>>(adj, wvu, wvuT, nf, normf, nmax, Wee, Wef, edge);
    k_layer<0><<<512, 256, 0, stream>>>(x0, x1, wvu, wvuT, normf, edge, Wm, Wu);
    k_layer<0><<<512, 256, 0, stream>>>(x1, x0, wvu, wvuT, normf, edge, Wm + 8192, Wu + 8192);
    k_layer<0><<<512, 256, 0, stream>>>(x0, x1, wvu, wvuT, normf, edge, Wm + 16384, Wu + 16384);
    k_layer<1><<<512, 256, 0, stream>>>(x1, out, wvu, wvuT, normf, edge, Wm + 24576, Wu + 24576);
}